// Round 12
// baseline (621.215 us; speedup 1.0000x reference)
//
#include <hip/hip_runtime.h>
#include <hip/hip_bf16.h>

// Problem constants (match reference)
#define NN 100000
#define NE 500000
#define RELS 4
#define NCLS 16
#define SCAN_B 1024
#define NCHUNK ((NN + SCAN_B - 1) / SCAN_B)   // 98

typedef __attribute__((ext_vector_type(8))) short s16x8;
typedef __attribute__((ext_vector_type(4))) float f32x4;

__device__ __forceinline__ float bf2f(unsigned short u) {
    return __uint_as_float(((unsigned int)u) << 16);
}
__device__ __forceinline__ unsigned short f2bfbits(float f) {
    __hip_bfloat16 h = __float2bfloat16(f);
    return *reinterpret_cast<unsigned short*>(&h);
}

// ---------------- CSR build (combined, weighted) ----------------
// counts[rel][dst] kept for weights; combined rowptr over dst; edge records
// col2[i] = { yidx = src*4+rel, w = 1/deg_rel(dst) } sorted by dst.

__global__ void hist_kernel(const int* __restrict__ e0, const int* __restrict__ e1,
                            const int* __restrict__ e2, const int* __restrict__ e3,
                            int* __restrict__ counts) {
    int i = blockIdx.x * 256 + threadIdx.x;
    int rel = blockIdx.y;
    if (i >= NE) return;
    const int* ep = (rel == 0) ? e0 : (rel == 1) ? e1 : (rel == 2) ? e2 : e3;
    int d = ep[NE + i];              // dst row
    atomicAdd(&counts[rel * NN + d], 1);
}

__global__ void scanA_kernel(const int* __restrict__ counts, int* __restrict__ bsums) {
    int chunk = blockIdx.x;
    int i = chunk * SCAN_B + threadIdx.x;
    __shared__ int s[SCAN_B];
    int v = 0;
    if (i < NN)
        v = counts[i] + counts[NN + i] + counts[2 * NN + i] + counts[3 * NN + i];
    s[threadIdx.x] = v;
    __syncthreads();
    for (int off = SCAN_B / 2; off > 0; off >>= 1) {
        if (threadIdx.x < off) s[threadIdx.x] += s[threadIdx.x + off];
        __syncthreads();
    }
    if (threadIdx.x == 0) bsums[chunk] = s[0];
}

__global__ void scanB_kernel(int* __restrict__ bsums, int* __restrict__ rowptr) {
    if (threadIdx.x == 0) {
        int acc = 0;
        for (int c = 0; c < NCHUNK; ++c) {
            int v = bsums[c];
            bsums[c] = acc;
            acc += v;
        }
        rowptr[NN] = acc;            // == 4*NE
    }
}

__global__ void scanC_kernel(const int* __restrict__ counts, const int* __restrict__ bsums,
                             int* __restrict__ rowptr) {
    int chunk = blockIdx.x;
    int i = chunk * SCAN_B + threadIdx.x;
    __shared__ int s[SCAN_B];
    int v = 0;
    if (i < NN)
        v = counts[i] + counts[NN + i] + counts[2 * NN + i] + counts[3 * NN + i];
    s[threadIdx.x] = v;
    __syncthreads();
    for (int off = 1; off < SCAN_B; off <<= 1) {
        int add = (threadIdx.x >= (unsigned)off) ? s[threadIdx.x - off] : 0;
        __syncthreads();
        s[threadIdx.x] += add;
        __syncthreads();
    }
    if (i < NN)
        rowptr[i] = bsums[chunk] + s[threadIdx.x] - v;
}

__global__ void fill_kernel(const int* __restrict__ e0, const int* __restrict__ e1,
                            const int* __restrict__ e2, const int* __restrict__ e3,
                            const int* __restrict__ rowptr, const int* __restrict__ counts,
                            int* __restrict__ cursor, int2* __restrict__ col2) {
    int i = blockIdx.x * 256 + threadIdx.x;
    int rel = blockIdx.y;
    if (i >= NE) return;
    const int* ep = (rel == 0) ? e0 : (rel == 1) ? e1 : (rel == 2) ? e2 : e3;
    int src = ep[i];
    int dst = ep[NE + i];
    int p = atomicAdd(&cursor[dst], 1);
    float w = 1.0f / (float)counts[rel * NN + dst];
    col2[rowptr[dst] + p] = make_int2(src * 4 + rel, __float_as_int(w));
}

// ---------------- weight conversion ----------------
// BT[l][n][k] (bf16, k contiguous, n = output col 0..639):
//   n<512  -> W_nbr[l][n>>7][k][n&127]
//   n>=512 -> sum_r W_root[l][r][k][n-512]
// bsum[l][c] = sum_r b_nbr[l][r][c]  (fp32)

__global__ void wconv_kernel(const float* __restrict__ Wn, const float* __restrict__ Wr,
                             const float* __restrict__ bn, __hip_bfloat16* __restrict__ BT,
                             float* __restrict__ bsum) {
    int idx = blockIdx.x * 256 + threadIdx.x;
    if (idx < 2 * 640 * 128) {
        int l = (idx >= 640 * 128) ? 1 : 0;
        int rem = idx - l * 640 * 128;
        int n = rem >> 7;
        int k = rem & 127;
        float v;
        if (n < 512) {
            v = Wn[(((size_t)l * RELS + (n >> 7)) * 128 + k) * 128 + (n & 127)];
        } else {
            v = 0.f;
            for (int r = 0; r < RELS; ++r)
                v += Wr[(((size_t)l * RELS + r) * 128 + k) * 128 + (n - 512)];
        }
        BT[((size_t)l * 640 + n) * 128 + k] = __float2bfloat16(v);
    } else if (idx < 2 * 640 * 128 + 256) {
        int i = idx - 2 * 640 * 128;
        int l = i >> 7, c = i & 127;
        float a = 0.f;
        for (int r = 0; r < RELS; ++r) a += bn[((size_t)l * RELS + r) * 128 + c];
        bsum[i] = a;
    }
}

// ---------------- dense GEMM: [Y | S] = A @ BTl^T ----------------
// A = x (fp32, layer 1) or h (bf16, layer 2). Y ROW-MAJOR [node][rel][128]
// (round-9 layout: best write behavior). hS = root-sum slice. Raw output.
// BM=64 rows/block, in-block loop over 5 col-tiles (A LDS-resident, loaded
// once). K=128 in 2 chunks of 64. 4 waves (2x2), wave 32x64 via 2x4
// mfma_f32_16x16x32_bf16. LDS 32 KB (A 16K + B 16K; C stages into dead B)
// -> 5 blocks/CU.

template <bool FP32A>
__global__ __launch_bounds__(256, 5) void dense_gemm_kernel(
    const void* __restrict__ Ain, __hip_bfloat16* __restrict__ Y,
    __hip_bfloat16* __restrict__ hS, const __hip_bfloat16* __restrict__ BTl, int M) {
    __shared__ uint4 smem4[2048];            // 32 KB
    char* AsB = (char*)smem4;                // [64 rows][128 k] bf16, swizzled
    char* BsB = (char*)smem4 + 16384;        // [128 n][64 k] per chunk; C reuses
    int t = threadIdx.x;
    int l = t & 63;
    int wave = t >> 6;
    int wm = wave >> 1, wn = wave & 1;
    int row0 = blockIdx.x * 64;

    int bn_ = t >> 1;                // B stage: n row 0..127
    int bj = t & 1;                  // B stage: 32-elem half
    int lrow = l & 15;               // MFMA fragment row/col within 16
    int lkg = l >> 4;                // MFMA k-group 0..3

    // ---- stage A tile: 64 rows x 256B(bf16); thread owns row t>>2, part t&3 ----
    {
        int row = t >> 2, part = t & 3;
        int grow = row0 + row;
        uint4 v[4] = {};
        if (grow < M) {
            if (FP32A) {
                const float* gx = (const float*)Ain + (size_t)grow * 128 + part * 32;
#pragma unroll
                for (int j = 0; j < 4; ++j) {
                    float4 f0 = *(const float4*)(gx + j * 8);
                    float4 f1 = *(const float4*)(gx + j * 8 + 4);
                    v[j].x = f2bfbits(f0.x) | ((unsigned)f2bfbits(f0.y) << 16);
                    v[j].y = f2bfbits(f0.z) | ((unsigned)f2bfbits(f0.w) << 16);
                    v[j].z = f2bfbits(f1.x) | ((unsigned)f2bfbits(f1.y) << 16);
                    v[j].w = f2bfbits(f1.z) | ((unsigned)f2bfbits(f1.w) << 16);
                }
            } else {
                const __hip_bfloat16* gh =
                    (const __hip_bfloat16*)Ain + (size_t)grow * 128 + part * 32;
#pragma unroll
                for (int j = 0; j < 4; ++j) v[j] = *(const uint4*)(gh + j * 8);
            }
        }
#pragma unroll
        for (int j = 0; j < 4; ++j) {
            int q = part * 4 + j;
            *(uint4*)(AsB + row * 256 + ((q ^ (row & 7)) << 4)) = v[j];
        }
    }

    uint4 breg[4];
    {   // preload B chunk 0 (ct=0, c=0)
        const __hip_bfloat16* gb = BTl + (size_t)bn_ * 128 + bj * 32;
#pragma unroll
        for (int j = 0; j < 4; ++j) breg[j] = *(const uint4*)(gb + j * 8);
    }

    f32x4 acc[2][4];
#pragma unroll
    for (int i = 0; i < 2; ++i)
#pragma unroll
        for (int j = 0; j < 4; ++j) acc[i][j] = (f32x4){0.f, 0.f, 0.f, 0.f};

    for (int ct = 0; ct < 5; ++ct) {
        for (int c = 0; c < 2; ++c) {
            __syncthreads();         // prior BsB readers done; A visible
#pragma unroll
            for (int j = 0; j < 4; ++j) {
                int q = bj * 4 + j;
                *(uint4*)(BsB + bn_ * 128 + ((q ^ (bn_ & 7)) << 4)) = breg[j];
            }
            int g10 = ct * 2 + c + 1;
            if (g10 < 10) {          // prefetch next B chunk under MFMA
                int ctn = g10 >> 1, cn = g10 & 1;
                const __hip_bfloat16* gb =
                    BTl + ((size_t)(ctn * 128 + bn_)) * 128 + cn * 64 + bj * 32;
#pragma unroll
                for (int j = 0; j < 4; ++j) breg[j] = *(const uint4*)(gb + j * 8);
            }
            __syncthreads();
#pragma unroll
            for (int kk = 0; kk < 2; ++kk) {
                s16x8 af[2], bfr[4];
                int qa = c * 8 + kk * 4 + lkg;
                int qb = kk * 4 + lkg;
#pragma unroll
                for (int mi = 0; mi < 2; ++mi) {
                    int row = wm * 32 + mi * 16 + lrow;
                    af[mi] = *(const s16x8*)(AsB + row * 256 + ((qa ^ (row & 7)) << 4));
                }
#pragma unroll
                for (int ni = 0; ni < 4; ++ni) {
                    int nrow = wn * 64 + ni * 16 + lrow;
                    bfr[ni] = *(const s16x8*)(BsB + nrow * 128 + ((qb ^ (nrow & 7)) << 4));
                }
#pragma unroll
                for (int mi = 0; mi < 2; ++mi)
#pragma unroll
                    for (int ni = 0; ni < 4; ++ni)
                        acc[mi][ni] = __builtin_amdgcn_mfma_f32_16x16x32_bf16(
                            af[mi], bfr[ni], acc[mi][ni], 0, 0, 0);
            }
        }
        __syncthreads();             // MFMA reads of BsB done; stage C into it
        {
            int cr = l >> 4;
            int cc = l & 15;
#pragma unroll
            for (int ni = 0; ni < 4; ++ni) {
                int colg = wn * 64 + ni * 16 + cc;
                int q = colg >> 3;
                int cb = (colg & 7) * 2;
#pragma unroll
                for (int mi = 0; mi < 2; ++mi) {
#pragma unroll
                    for (int r = 0; r < 4; ++r) {
                        int row = wm * 32 + mi * 16 + cr * 4 + r;
                        int byte = row * 256 + ((q ^ (row & 15)) << 4) + cb;
                        *(unsigned short*)(BsB + byte) = f2bfbits(acc[mi][ni][r]);
                    }
                }
            }
#pragma unroll
            for (int mi = 0; mi < 2; ++mi)
#pragma unroll
                for (int ni = 0; ni < 4; ++ni) acc[mi][ni] = (f32x4){0.f, 0.f, 0.f, 0.f};
        }
        __syncthreads();
        {   // contiguous 64B stores, row-major Y[node][rel][128] (or hS for ct==4)
            int row = t >> 2;
            int part = t & 3;
            int grow = row0 + row;
            if (grow < M) {
                __hip_bfloat16* dst = (ct < 4)
                    ? (Y + (size_t)grow * 512 + ct * 128 + part * 32)
                    : (hS + (size_t)grow * 128 + part * 32);
#pragma unroll
                for (int j = 0; j < 4; ++j) {
                    int q = part * 4 + j;
                    uint4 v = *(const uint4*)(BsB + row * 256 + ((q ^ (row & 15)) << 4));
                    *(uint4*)(dst + j * 8) = v;
                }
            }
        }
    }
}

// ---------------- gather-finish: h = relu(0.25*(sum_e w_e*Y[yidx_e] + S + bias)) ----------------
// Combined weighted edge list: one loop of ~20 edges/node, unroll-4 -> 4
// independent Y-row gathers continuously in flight. Y row-major: edge row at
// yidx*128 elements (yidx = src*4+rel). 16 lanes x 16B per node, 16 nodes per
// 256-thread block. No LDS, no barriers.

__global__ void gather_finish_kernel(const int* __restrict__ rowptr2,
                                     const int2* __restrict__ col2,
                                     const __hip_bfloat16* __restrict__ Y,
                                     __hip_bfloat16* __restrict__ hS,
                                     const float* __restrict__ bsum) {
    int t = threadIdx.x;
    int node = blockIdx.x * 16 + (t >> 4);
    int lane = t & 15;
    const __hip_bfloat16* __restrict__ ys = Y + lane * 8;
    float acc[8];
    {
        uint4 sv = *(const uint4*)(hS + (size_t)node * 128 + lane * 8);
        acc[0] = bf2f(sv.x & 0xffff); acc[1] = bf2f(sv.x >> 16);
        acc[2] = bf2f(sv.y & 0xffff); acc[3] = bf2f(sv.y >> 16);
        acc[4] = bf2f(sv.z & 0xffff); acc[5] = bf2f(sv.z >> 16);
        acc[6] = bf2f(sv.w & 0xffff); acc[7] = bf2f(sv.w >> 16);
        const float* bs = bsum + lane * 8;
#pragma unroll
        for (int j = 0; j < 8; ++j) acc[j] += bs[j];
    }
    int s = rowptr2[node], e = rowptr2[node + 1];
    int k = s;
    for (; k + 4 <= e; k += 4) {
        int2 d0 = col2[k], d1 = col2[k + 1], d2 = col2[k + 2], d3 = col2[k + 3];
        uint4 v0 = *(const uint4*)(ys + (size_t)d0.x * 128);
        uint4 v1 = *(const uint4*)(ys + (size_t)d1.x * 128);
        uint4 v2 = *(const uint4*)(ys + (size_t)d2.x * 128);
        uint4 v3 = *(const uint4*)(ys + (size_t)d3.x * 128);
        float w0 = __int_as_float(d0.y), w1 = __int_as_float(d1.y);
        float w2 = __int_as_float(d2.y), w3 = __int_as_float(d3.y);
        acc[0] += w0 * bf2f(v0.x & 0xffff) + w1 * bf2f(v1.x & 0xffff)
                + w2 * bf2f(v2.x & 0xffff) + w3 * bf2f(v3.x & 0xffff);
        acc[1] += w0 * bf2f(v0.x >> 16)    + w1 * bf2f(v1.x >> 16)
                + w2 * bf2f(v2.x >> 16)    + w3 * bf2f(v3.x >> 16);
        acc[2] += w0 * bf2f(v0.y & 0xffff) + w1 * bf2f(v1.y & 0xffff)
                + w2 * bf2f(v2.y & 0xffff) + w3 * bf2f(v3.y & 0xffff);
        acc[3] += w0 * bf2f(v0.y >> 16)    + w1 * bf2f(v1.y >> 16)
                + w2 * bf2f(v2.y >> 16)    + w3 * bf2f(v3.y >> 16);
        acc[4] += w0 * bf2f(v0.z & 0xffff) + w1 * bf2f(v1.z & 0xffff)
                + w2 * bf2f(v2.z & 0xffff) + w3 * bf2f(v3.z & 0xffff);
        acc[5] += w0 * bf2f(v0.z >> 16)    + w1 * bf2f(v1.z >> 16)
                + w2 * bf2f(v2.z >> 16)    + w3 * bf2f(v3.z >> 16);
        acc[6] += w0 * bf2f(v0.w & 0xffff) + w1 * bf2f(v1.w & 0xffff)
                + w2 * bf2f(v2.w & 0xffff) + w3 * bf2f(v3.w & 0xffff);
        acc[7] += w0 * bf2f(v0.w >> 16)    + w1 * bf2f(v1.w >> 16)
                + w2 * bf2f(v2.w >> 16)    + w3 * bf2f(v3.w >> 16);
    }
    for (; k < e; ++k) {
        int2 d0 = col2[k];
        uint4 v0 = *(const uint4*)(ys + (size_t)d0.x * 128);
        float w0 = __int_as_float(d0.y);
        acc[0] += w0 * bf2f(v0.x & 0xffff); acc[1] += w0 * bf2f(v0.x >> 16);
        acc[2] += w0 * bf2f(v0.y & 0xffff); acc[3] += w0 * bf2f(v0.y >> 16);
        acc[4] += w0 * bf2f(v0.z & 0xffff); acc[5] += w0 * bf2f(v0.z >> 16);
        acc[6] += w0 * bf2f(v0.w & 0xffff); acc[7] += w0 * bf2f(v0.w >> 16);
    }
    uint4 o;
    float v0 = fmaxf(acc[0] * 0.25f, 0.f), v1 = fmaxf(acc[1] * 0.25f, 0.f);
    float v2 = fmaxf(acc[2] * 0.25f, 0.f), v3 = fmaxf(acc[3] * 0.25f, 0.f);
    float v4 = fmaxf(acc[4] * 0.25f, 0.f), v5 = fmaxf(acc[5] * 0.25f, 0.f);
    float v6 = fmaxf(acc[6] * 0.25f, 0.f), v7 = fmaxf(acc[7] * 0.25f, 0.f);
    o.x = f2bfbits(v0) | ((unsigned)f2bfbits(v1) << 16);
    o.y = f2bfbits(v2) | ((unsigned)f2bfbits(v3) << 16);
    o.z = f2bfbits(v4) | ((unsigned)f2bfbits(v5) << 16);
    o.w = f2bfbits(v6) | ((unsigned)f2bfbits(v7) << 16);
    *(uint4*)(hS + (size_t)node * 128 + lane * 8) = o;
}

// ---------------- final linear: out[M,16] = h[M,128] @ W[128,16] + b ----------------

__global__ void final_linear_kernel(const __hip_bfloat16* __restrict__ h,
                                    const float* __restrict__ W,
                                    const float* __restrict__ bias, float* __restrict__ out) {
    __shared__ float Ws[128 * 16];
    __shared__ float Hs[16 * 132];
    int tid = threadIdx.x;
    int node0 = blockIdx.x * 16;
    for (int i = tid; i < 2048; i += 256) Ws[i] = W[i];
    {
        int g = tid >> 4, c = tid & 15;
        int node = node0 + g;
        float f[8] = {};
        if (node < NN) {
            uint4 v = *(const uint4*)(h + (size_t)node * 128 + c * 8);
            f[0] = bf2f(v.x & 0xffff); f[1] = bf2f(v.x >> 16);
            f[2] = bf2f(v.y & 0xffff); f[3] = bf2f(v.y >> 16);
            f[4] = bf2f(v.z & 0xffff); f[5] = bf2f(v.z >> 16);
            f[6] = bf2f(v.w & 0xffff); f[7] = bf2f(v.w >> 16);
        }
#pragma unroll
        for (int j = 0; j < 8; ++j) Hs[g * 132 + c * 8 + j] = f[j];
    }
    __syncthreads();
    int g = tid >> 4;
    int c = tid & 15;
    int node = node0 + g;
    if (node >= NN) return;
    float acc = bias[c];
#pragma unroll 8
    for (int k = 0; k < 128; ++k) acc += Hs[g * 132 + k] * Ws[k * 16 + c];
    out[node * NCLS + c] = acc;
}

// ---------------- launch ----------------

extern "C" void kernel_launch(void* const* d_in, const int* in_sizes, int n_in,
                              void* d_out, int out_size, void* d_ws, size_t ws_size,
                              hipStream_t stream) {
    const float* x     = (const float*)d_in[0];
    const int*   e0    = (const int*)d_in[1];
    const int*   e1    = (const int*)d_in[2];
    const int*   e2    = (const int*)d_in[3];
    const int*   e3    = (const int*)d_in[4];
    const float* W_nbr = (const float*)d_in[5];
    const float* b_nbr = (const float*)d_in[6];
    const float* W_root= (const float*)d_in[7];
    const float* lin_w = (const float*)d_in[8];
    const float* lin_b = (const float*)d_in[9];
    float* out = (float*)d_out;

    // workspace bump allocator (256B aligned)
    char* p = (char*)d_ws;
    auto alloc = [&](size_t bytes) -> void* {
        void* q = (void*)p;
        p += (bytes + 255) & ~(size_t)255;
        return q;
    };
    int*   counts  = (int*)alloc((size_t)RELS * NN * 4);
    int*   cursor  = (int*)alloc((size_t)NN * 4);
    int*   rowptr2 = (int*)alloc((size_t)(NN + 1) * 4);
    int*   bsums   = (int*)alloc((size_t)128 * 4);
    float* bsum    = (float*)alloc((size_t)2 * 128 * 4);
    int2*  col2    = (int2*)alloc((size_t)RELS * NE * 8);               // 16 MB
    __hip_bfloat16* BT = (__hip_bfloat16*)alloc((size_t)2 * 640 * 128 * 2);
    __hip_bfloat16* Y  = (__hip_bfloat16*)alloc((size_t)NN * 512 * 2);  // 102.4 MB
    __hip_bfloat16* hA = (__hip_bfloat16*)alloc((size_t)NN * 128 * 2);
    __hip_bfloat16* hB = (__hip_bfloat16*)alloc((size_t)NN * 128 * 2);

    const int eblocks = (NE + 255) / 256;

    // combined weighted CSR build (shared by both layers)
    hipMemsetAsync(counts, 0, (size_t)RELS * NN * 4, stream);
    hipMemsetAsync(cursor, 0, (size_t)NN * 4, stream);
    hist_kernel<<<dim3(eblocks, RELS), 256, 0, stream>>>(e0, e1, e2, e3, counts);
    scanA_kernel<<<NCHUNK, SCAN_B, 0, stream>>>(counts, bsums);
    scanB_kernel<<<1, 64, 0, stream>>>(bsums, rowptr2);
    scanC_kernel<<<NCHUNK, SCAN_B, 0, stream>>>(counts, bsums, rowptr2);
    fill_kernel<<<dim3(eblocks, RELS), 256, 0, stream>>>(e0, e1, e2, e3, rowptr2,
                                                         counts, cursor, col2);

    // weights -> bf16 transposed (+ root-sum fold + bias sum)
    wconv_kernel<<<(2 * 640 * 128 + 256 + 255) / 256, 256, 0, stream>>>(
        W_nbr, W_root, b_nbr, BT, bsum);

    const int rblocks = (NN + 63) / 64;   // 1563
    const int nblocks = NN / 16;          // 6250, exact

    // layer 1: x (fp32) -> (Y, hB=S) -> hB = h1
    dense_gemm_kernel<true><<<rblocks, 256, 0, stream>>>(x, Y, hB, BT, NN);
    gather_finish_kernel<<<nblocks, 256, 0, stream>>>(rowptr2, col2, Y, hB, bsum);
    // layer 2: hB -> (Y, hA=S) -> hA = h2
    dense_gemm_kernel<false><<<rblocks, 256, 0, stream>>>(hB, Y, hA, BT + (size_t)640 * 128, NN);
    gather_finish_kernel<<<nblocks, 256, 0, stream>>>(rowptr2, col2, Y, hA, bsum + 128);

    final_linear_kernel<<<(NN + 15) / 16, 256, 0, stream>>>(hA, lin_w, lin_b, out);
}